// Round 1
// 847.548 us; speedup vs baseline: 1.0227x; 1.0227x over previous
//
#include <hip/hip_runtime.h>
#include <hip/hip_bf16.h>
#include <stdint.h>

#define TOKENS 2048
#define DMODEL 1024
#define HID    2048
#define NEXP   8
#define VOCAB  32000
#define ROWCAP 5120      // 4096 rows + 8*127 pad, rounded to 40*128
#define MAXTILES 40
#define LN_EPS 1e-5f

typedef __hip_bfloat16 bf16;
typedef __bf16 v8bf __attribute__((ext_vector_type(8)));
typedef float  v4f  __attribute__((ext_vector_type(4)));

// control block (ints) at ws offset 0
#define CTL_COUNTS 0    // 8
#define CTL_CURSOR 8    // 8
#define CTL_PADOFF 16   // 9
#define CTL_TILE2E 32   // 40
#define CTL_NTILES 72
#define CTL_INTS   80

typedef __attribute__((address_space(3))) uint32_t lds_u32_t;
typedef __attribute__((address_space(1))) uint32_t glb_u32_t;

__device__ __forceinline__ void gl2lds16(const void* g, void* l) {
  // async global->LDS, 16B per lane; LDS dst is wave-uniform base + lane*16
  __builtin_amdgcn_global_load_lds((glb_u32_t*)(uintptr_t)g,
                                   (lds_u32_t*)(uintptr_t)l, 16, 0, 0);
}

// ---------------- embed gather + gate softmax + top2 ----------------
__global__ __launch_bounds__(256) void embed_gate(
    const int* __restrict__ x, const float* __restrict__ embed,
    const float* __restrict__ Wg, const float* __restrict__ bg,
    bf16* __restrict__ h_bf, int* __restrict__ top2i, float* __restrict__ top2w,
    int* __restrict__ ctl)
{
  const int t = blockIdx.x, tid = threadIdx.x;
  const int xid = x[t];
  const float4 hv = ((const float4*)(embed + (size_t)xid * DMODEL))[tid];

  union { ushort4 u; bf16 b[4]; } pk;
  pk.b[0] = __float2bfloat16(hv.x); pk.b[1] = __float2bfloat16(hv.y);
  pk.b[2] = __float2bfloat16(hv.z); pk.b[3] = __float2bfloat16(hv.w);
  ((ushort4*)(h_bf + (size_t)t * DMODEL))[tid] = pk.u;

  float acc[8] = {0,0,0,0,0,0,0,0};
  const float hk[4] = {hv.x, hv.y, hv.z, hv.w};
  #pragma unroll
  for (int u = 0; u < 4; ++u) {
    const float* wr = Wg + (size_t)(tid*4 + u) * NEXP;
    #pragma unroll
    for (int e = 0; e < 8; ++e) acc[e] += hk[u] * wr[e];
  }
  #pragma unroll
  for (int e = 0; e < 8; ++e)
    for (int off = 32; off >= 1; off >>= 1)
      acc[e] += __shfl_down(acc[e], off, 64);

  __shared__ float sred[4][8];
  const int lane = tid & 63, wave = tid >> 6;
  if (lane == 0) {
    #pragma unroll
    for (int e = 0; e < 8; ++e) sred[wave][e] = acc[e];
  }
  __syncthreads();
  if (tid == 0) {
    float lg[8];
    #pragma unroll
    for (int e = 0; e < 8; ++e)
      lg[e] = sred[0][e] + sred[1][e] + sred[2][e] + sred[3][e] + bg[e];
    float m = lg[0];
    #pragma unroll
    for (int e = 1; e < 8; ++e) m = fmaxf(m, lg[e]);
    float p[8], s = 0.f;
    #pragma unroll
    for (int e = 0; e < 8; ++e) { p[e] = expf(lg[e] - m); s += p[e]; }
    const float inv = 1.f / s;
    int i0 = 0;
    for (int e = 1; e < 8; ++e) if (p[e] > p[i0]) i0 = e;
    int i1 = -1;
    for (int e = 0; e < 8; ++e) { if (e == i0) continue; if (i1 < 0 || p[e] > p[i1]) i1 = e; }
    top2i[2*t] = i0; top2i[2*t+1] = i1;
    top2w[2*t] = p[i0]*inv; top2w[2*t+1] = p[i1]*inv;
    atomicAdd(&ctl[CTL_COUNTS + i0], 1);
    atomicAdd(&ctl[CTL_COUNTS + i1], 1);
  }
}

// ---------------- bucket tokens per expert (128-aligned segments) ----------------
__global__ __launch_bounds__(256) void scatter_k(
    const int* __restrict__ top2i, int* __restrict__ ctl,
    int* __restrict__ tok2row, int* __restrict__ rowtok)
{
  __shared__ int spad[8];
  const int tid = threadIdx.x;
  for (int r = tid; r < ROWCAP; r += 256) rowtok[r] = 0;   // pad rows -> token 0 (harmless)
  if (tid == 0) {
    int off = 0, gm = 0;
    for (int e = 0; e < 8; ++e) {
      spad[e] = off; ctl[CTL_PADOFF + e] = off;
      int nt = (ctl[CTL_COUNTS + e] + 127) >> 7;
      for (int i = 0; i < nt; ++i) ctl[CTL_TILE2E + gm++] = e;
      off += nt << 7;
    }
    ctl[CTL_PADOFF + 8] = off;
    ctl[CTL_NTILES] = gm;
  }
  __syncthreads();
  for (int idx = tid; idx < 2*TOKENS; idx += 256) {
    const int e = top2i[idx];
    const int pos = spad[e] + atomicAdd(&ctl[CTL_CURSOR + e], 1);
    tok2row[idx] = pos;
    rowtok[pos] = idx >> 1;
  }
}

// ---------------- fp32 [b][R][C] -> bf16 [b][C][R] (B^T layout for MFMA) ----------------
__global__ __launch_bounds__(256) void transpose_cvt(
    const float* __restrict__ in, bf16* __restrict__ out, int R, int C)
{
  __shared__ float tile[32][33];
  const int b = blockIdx.z;
  in  += (size_t)b * R * C;
  out += (size_t)b * R * C;
  const int ct = blockIdx.x * 32, rt = blockIdx.y * 32;
  const int lc = threadIdx.x & 31, lr = threadIdx.x >> 5;  // 0..31, 0..7
  #pragma unroll
  for (int i = 0; i < 4; ++i) {
    const int r = lr + i*8;
    tile[r][lc] = in[(size_t)(rt + r) * C + ct + lc];
  }
  __syncthreads();
  #pragma unroll
  for (int i = 0; i < 4; ++i) {
    const int r = lr + i*8;
    out[(size_t)(ct + r) * R + rt + lc] = __float2bfloat16(tile[lc][r]);
  }
}

// ---------------- 128x128x32 bf16 MFMA GEMM (m97 structure) ----------------
// MODE 0: a_act = relu(h[rowtok] @ W1t[e]^T + b1[e])  K=1024 N=2048, bf16 out
// MODE 1: y     =       a_act @ W2t[e]^T + b2[e]      K=2048 N=1024, f32 out
template<int MODE>
__global__ __launch_bounds__(256) void gemm128(
    const bf16* __restrict__ Abase, const bf16* __restrict__ Btbase,
    const float* __restrict__ bias, float* __restrict__ outF, bf16* __restrict__ outB,
    const int* __restrict__ ctl, const int* __restrict__ rowtok)
{
  constexpr int K = (MODE == 1) ? HID : DMODEL;
  constexpr int N = (MODE == 0) ? HID : DMODEL;
  const int gm = blockIdx.x, gn = blockIdx.y;

  int eid = 0;
  if (gm >= ctl[CTL_NTILES]) return;
  eid = ctl[CTL_TILE2E + gm];

  __shared__ bf16 As[128 * 32];
  __shared__ bf16 Bs[128 * 32];
  __shared__ int  rts[128];

  const int tid = threadIdx.x, lane = tid & 63, wave = tid >> 6;
  const bf16* Bt = Btbase + (size_t)eid * (size_t)N * K + (size_t)(gn * 128) * K;
  const float* bv = bias + (size_t)eid * N + gn * 128;

  if constexpr (MODE == 0) {
    if (tid < 128) rts[tid] = rowtok[gm * 128 + tid];
    __syncthreads();
  }

  // staging coords: chunk c = 16 rows; wave handles chunks {wave, wave+4}
  const int srow = lane >> 2;          // row within chunk
  const int scol = (lane & 3) * 8;     // bf16 col offset (16B granules)
  const int r0 = wave * 16 + srow, r1 = (wave + 4) * 16 + srow;
  size_t ga0, ga1;
  if constexpr (MODE == 0) { ga0 = (size_t)rts[r0]; ga1 = (size_t)rts[r1]; }
  else { ga0 = (size_t)(gm * 128 + r0); ga1 = (size_t)(gm * 128 + r1); }
  const bf16* aptr0 = Abase + ga0 * K + scol;
  const bf16* aptr1 = Abase + ga1 * K + scol;
  const bf16* bptr0 = Bt + (size_t)r0 * K + scol;
  const bf16* bptr1 = Bt + (size_t)r1 * K + scol;

  const int wm = (wave & 1) * 64, wn = (wave >> 1) * 64;
  const int lr = lane & 15, lq = lane >> 4;

  v4f acc[4][4] = {};

  for (int k0 = 0; k0 < K; k0 += 32) {
    gl2lds16(aptr0 + k0, &As[wave * 512]);
    gl2lds16(aptr1 + k0, &As[(wave + 4) * 512]);
    gl2lds16(bptr0 + k0, &Bs[wave * 512]);
    gl2lds16(bptr1 + k0, &Bs[(wave + 4) * 512]);
    __syncthreads();

    v8bf af[4], bfg[4];
    #pragma unroll
    for (int i = 0; i < 4; ++i) af[i]  = *(const v8bf*)&As[(wm + i*16 + lr) * 32 + lq * 8];
    #pragma unroll
    for (int j = 0; j < 4; ++j) bfg[j] = *(const v8bf*)&Bs[(wn + j*16 + lr) * 32 + lq * 8];
    #pragma unroll
    for (int i = 0; i < 4; ++i)
      #pragma unroll
      for (int j = 0; j < 4; ++j)
        acc[i][j] = __builtin_amdgcn_mfma_f32_16x16x32_bf16(af[i], bfg[j], acc[i][j], 0, 0, 0);
    __syncthreads();
  }

  float bb[4];
  #pragma unroll
  for (int j = 0; j < 4; ++j) bb[j] = bv[wn + j*16 + lr];

  #pragma unroll
  for (int i = 0; i < 4; ++i) {
    #pragma unroll
    for (int j = 0; j < 4; ++j) {
      #pragma unroll
      for (int r = 0; r < 4; ++r) {
        const int row = gm * 128 + wm + i*16 + lq*4 + r;
        const int col = gn * 128 + wn + j*16 + lr;
        float v = acc[i][j][r] + bb[j];
        if constexpr (MODE == 0) {
          v = v > 0.f ? v : 0.f;
          outB[(size_t)row * N + col] = __float2bfloat16(v);
        } else {
          outF[(size_t)row * (size_t)N + col] = v;
        }
      }
    }
  }
}

// ================= 256x256x64 8-phase head GEMM (T1+T2+T3+T4+T5) =================
// out[2048][32000] = lnb[2048][1024] @ Wht[32000][1024]^T + bh
// 8 waves (2M x 4N), per-wave 128x64 output. LDS 128KB: 2 dbuf x (A 32KB + B 32KB).
// LDS layout per matrix per buffer: [half h:2][kk:2][row:128][64B]  (kk-split 64B rows
//   -> ds_read_b128 frag loads land one granule per bank-quad: conflict-free, no XOR).
// Pipeline: per K-tile 4 phases; A(kt+1) halves staged at ph0/ph1 (region dead since
//   kt-1 ph2), B(kt+2) halves staged at ph2/ph3 into CURRENT buffer's B region (dead
//   after ph1). Single counted s_waitcnt vmcnt(4) per K-tile keeps 2 half-tiles in
//   flight across every boundary -- never vmcnt(0) in steady state.

__device__ __forceinline__ void stageAB(const bf16* g, char* l) {
  gl2lds16(g,      l);          // kk=0 plane
  gl2lds16(g + 32, l + 8192);   // kk=1 plane
}

#define SBAR() do { __builtin_amdgcn_sched_barrier(0); \
                    __builtin_amdgcn_s_barrier();       \
                    __builtin_amdgcn_sched_barrier(0); } while (0)

__global__ __launch_bounds__(512, 2) void gemm256(
    const bf16* __restrict__ A, const bf16* __restrict__ Bt,
    const float* __restrict__ bias, float* __restrict__ out)
{
  extern __shared__ char smem[];
  constexpr int K = DMODEL;        // 1024
  constexpr int N = VOCAB;         // 32000
  constexpr int NK = K / 64;       // 16

  // XCD-chunked swizzle: 1000 wgs = 8 XCDs x 125; within a chunk m is fastest so
  // each XCD keeps the full 4MB A in its L2 and streams B panels once.
  const int orig = blockIdx.y * 8 + blockIdx.x;
  const int p = (orig & 7) * 125 + (orig >> 3);
  const int tm0 = (p & 7) * 256;
  const int tn0 = (p >> 3) * 256;

  const int tid = threadIdx.x;
  const int lane = tid & 63, wv = tid >> 6;
  const int lr = lane & 15, lq = lane >> 4;
  const int wr = wv >> 2, wc = wv & 3;

  // staging: thread t covers 16B granule t of each 8KB kk-plane
  const int r_s = tid >> 2;                 // 0..127 row within half
  const int c_s = (tid & 3) * 8;            // bf16 col within 32-col plane
  const bf16* aG = A  + (size_t)(tm0 + r_s) * K + c_s;
  const bf16* bG = Bt + (size_t)(tn0 + r_s) * K + c_s;
  char* lW = smem + wv * 1024;              // wave-uniform 1KB window in each plane

  // fragment-read byte bases (add db*65536 + kk*8192 + frag*1024)
  const int aOff = wr * 16384 + lr * 64 + lq * 16;
  const int bOff = 32768 + (wc >> 1) * 16384 + ((wc & 1) * 64 + lr) * 64 + lq * 16;

  v4f acc[8][4] = {};
  v8bf Af[4][2], Bf[4][2];

  // ---- prologue: stage tiles 0 (buf0) and 1 (buf1) = 16 loads/thread ----
  stageAB(aG,          lW);                       // A(0) h0
  stageAB(aG + 131072, lW + 16384);               // A(0) h1   (131072 = 128*K elems)
  stageAB(bG,          lW + 32768);               // B(0) h0
  stageAB(bG + 131072, lW + 32768 + 16384);       // B(0) h1
  stageAB(aG + 64,           lW + 65536);             // A(1) h0
  stageAB(aG + 131072 + 64,  lW + 65536 + 16384);     // A(1) h1
  stageAB(bG + 64,           lW + 65536 + 32768);     // B(1) h0
  stageAB(bG + 131072 + 64,  lW + 65536 + 32768 + 16384); // B(1) h1
  asm volatile("s_waitcnt vmcnt(8)" ::: "memory");  // tile 0 arrived; tile 1 in flight
  __builtin_amdgcn_s_barrier();
  __builtin_amdgcn_sched_barrier(0);

  for (int kt = 0; kt < NK; ++kt) {
    const int db = kt & 1;
    const char* sA = smem + db * 65536 + aOff;
    const char* sB = smem + db * 65536 + bOff;
    char* lwA = lW + (db ^ 1) * 65536;              // A(kt+1) -> other buffer
    char* lwB = lW + db * 65536 + 32768;            // B(kt+2) -> same-parity buffer
    const int kN1 = (kt + 1) * 64;
    const int kN2 = (kt + 2) * 64;
    const bool stA = (kt > 0) & (kt + 1 < NK);      // kt==0: A(1) staged in prologue
    const bool stB = (kt + 2 < NK);

    // ---- phase 0: read A m0-3 + B n0-1 (12 reads) | stage A(kt+1) h0 ----
    #pragma unroll
    for (int mi = 0; mi < 4; ++mi)
      #pragma unroll
      for (int kk = 0; kk < 2; ++kk)
        Af[mi][kk] = *(const v8bf*)(sA + kk * 8192 + mi * 1024);
    #pragma unroll
    for (int n = 0; n < 2; ++n)
      #pragma unroll
      for (int kk = 0; kk < 2; ++kk)
        Bf[n][kk] = *(const v8bf*)(sB + kk * 8192 + n * 1024);
    if (stA) stageAB(aG + kN1, lwA);
    SBAR();
    __builtin_amdgcn_s_setprio(1);
    #pragma unroll
    for (int mi = 0; mi < 4; ++mi)
      #pragma unroll
      for (int n = 0; n < 2; ++n) {
        acc[mi][n] = __builtin_amdgcn_mfma_f32_16x16x32_bf16(Af[mi][0], Bf[n][0], acc[mi][n], 0, 0, 0);
        acc[mi][n] = __builtin_amdgcn_mfma_f32_16x16x32_bf16(Af[mi][1], Bf[n][1], acc[mi][n], 0, 0, 0);
      }
    __builtin_amdgcn_s_setprio(0);
    SBAR();

    // ---- phase 1: read B n2-3 (4 reads) | stage A(kt+1) h1 ----
    #pragma unroll
    for (int n = 2; n < 4; ++n)
      #pragma unroll
      for (int kk = 0; kk < 2; ++kk)
        Bf[n][kk] = *(const v8bf*)(sB + kk * 8192 + n * 1024);
    if (stA) stageAB(aG + 131072 + kN1, lwA + 16384);
    SBAR();
    __builtin_amdgcn_s_setprio(1);
    #pragma unroll
    for (int mi = 0; mi < 4; ++mi)
      #pragma unroll
      for (int n = 2; n < 4; ++n) {
        acc[mi][n] = __builtin_amdgcn_mfma_f32_16x16x32_bf16(Af[mi][0], Bf[n][0], acc[mi][n], 0, 0, 0);
        acc[mi][n] = __builtin_amdgcn_mfma_f32_16x16x32_bf16(Af[mi][1], Bf[n][1], acc[mi][n], 0, 0, 0);
      }
    __builtin_amdgcn_s_setprio(0);
    SBAR();

    // ---- phase 2: read A m4-7 (8 reads) | stage B(kt+2) h0 (B region dead) ----
    #pragma unroll
    for (int mi = 0; mi < 4; ++mi)
      #pragma unroll
      for (int kk = 0; kk < 2; ++kk)
        Af[mi][kk] = *(const v8bf*)(sA + kk * 8192 + (4 + mi) * 1024);
    if (stB) stageAB(bG + kN2, lwB);
    SBAR();
    __builtin_amdgcn_s_setprio(1);
    #pragma unroll
    for (int mi = 0; mi < 4; ++mi)
      #pragma unroll
      for (int n = 2; n < 4; ++n) {
        acc[4 + mi][n] = __builtin_amdgcn_mfma_f32_16x16x32_bf16(Af[mi][0], Bf[n][0], acc[4 + mi][n], 0, 0, 0);
        acc[4 + mi][n] = __builtin_amdgcn_mfma_f32_16x16x32_bf16(Af[mi][1], Bf[n][1], acc[4 + mi][n], 0, 0, 0);
      }
    __builtin_amdgcn_s_setprio(0);
    SBAR();

    // ---- phase 3: stage B(kt+2) h1 | MFMA m4-7 x n0-1 | counted vmcnt boundary ----
    if (stB) stageAB(bG + 131072 + kN2, lwB + 16384);
    SBAR();
    __builtin_amdgcn_s_setprio(1);
    #pragma unroll
    for (int mi = 0; mi < 4; ++mi)
      #pragma unroll
      for (int n = 0; n < 2; ++n) {
        acc[4 + mi][n] = __builtin_amdgcn_mfma_f32_16x16x32_bf16(Af[mi][0], Bf[n][0], acc[4 + mi][n], 0, 0, 0);
        acc[4 + mi][n] = __builtin_amdgcn_mfma_f32_16x16x32_bf16(Af[mi][1], Bf[n][1], acc[4 + mi][n], 0, 0, 0);
      }
    __builtin_amdgcn_s_setprio(0);
    __builtin_amdgcn_sched_barrier(0);
    // boundary: A(kt+1)+B(kt+1) must have arrived; B(kt+2) (newest 4 loads) stays in flight
    if (stB) { asm volatile("s_waitcnt vmcnt(4)" ::: "memory"); }
    else     { asm volatile("s_waitcnt vmcnt(0)" ::: "memory"); }
    __builtin_amdgcn_s_barrier();
    __builtin_amdgcn_sched_barrier(0);
  }

  // ---- epilogue: bias + fp32 store ----
  const int col0 = tn0 + wc * 64 + lr;
  const size_t row0 = (size_t)(tm0 + wr * 128 + lq * 4);
  float bb[4];
  #pragma unroll
  for (int n = 0; n < 4; ++n) bb[n] = bias[col0 + n * 16];
  #pragma unroll
  for (int mi = 0; mi < 8; ++mi)
    #pragma unroll
    for (int n = 0; n < 4; ++n)
      #pragma unroll
      for (int rr = 0; rr < 4; ++rr)
        out[(row0 + mi * 16 + rr) * (size_t)N + col0 + n * 16] = acc[mi][n][rr] + bb[n];
}

// ---------------- combine top2 expert outputs + LayerNorm -> bf16 ----------------
__global__ __launch_bounds__(256) void combine_ln(
    const float* __restrict__ y, const int* __restrict__ tok2row,
    const float* __restrict__ top2w, const float* __restrict__ gamma,
    const float* __restrict__ beta, bf16* __restrict__ ln)
{
  const int t = blockIdx.x, tid = threadIdx.x;
  const int rr0 = tok2row[2*t], rr1 = tok2row[2*t+1];
  const float w0 = top2w[2*t], w1 = top2w[2*t+1];
  const float4 a = ((const float4*)(y + (size_t)rr0 * DMODEL))[tid];
  const float4 b = ((const float4*)(y + (size_t)rr1 * DMODEL))[tid];
  const float c0 = w0*a.x + w1*b.x, c1 = w0*a.y + w1*b.y;
  const float c2 = w0*a.z + w1*b.z, c3 = w0*a.w + w1*b.w;

  float s1 = c0 + c1 + c2 + c3;
  float s2 = c0*c0 + c1*c1 + c2*c2 + c3*c3;
  for (int off = 32; off >= 1; off >>= 1) {
    s1 += __shfl_down(s1, off, 64);
    s2 += __shfl_down(s2, off, 64);
  }
  __shared__ float rs1[4], rs2[4];
  __shared__ float smu, srs;
  const int lane = tid & 63, wave = tid >> 6;
  if (lane == 0) { rs1[wave] = s1; rs2[wave] = s2; }
  __syncthreads();
  if (tid == 0) {
    const float S1 = rs1[0] + rs1[1] + rs1[2] + rs1[3];
    const float S2 = rs2[0] + rs2[1] + rs2[2] + rs2[3];
    const float mu = S1 / DMODEL;
    const float var = S2 / DMODEL - mu * mu;
    smu = mu; srs = rsqrtf(var + LN_EPS);
  }
  __syncthreads();
  const float mu = smu, rstd = srs;
  const float4 g  = ((const float4*)gamma)[tid];
  const float4 be = ((const float4*)beta)[tid];
  union { ushort4 u; bf16 bb[4]; } pk;
  pk.bb[0] = __float2bfloat16((c0 - mu) * rstd * g.x + be.x);
  pk.bb[1] = __float2bfloat16((c1 - mu) * rstd * g.y + be.y);
  pk.bb[2] = __float2bfloat16((c2 - mu) * rstd * g.z + be.z);
  pk.bb[3] = __float2bfloat16((c3 - mu) * rstd * g.w + be.w);
  ((ushort4*)(ln + (size_t)t * DMODEL))[tid] = pk.u;
}

// ---------------- host ----------------
extern "C" void kernel_launch(void* const* d_in, const int* in_sizes, int n_in,
                              void* d_out, int out_size, void* d_ws, size_t ws_size,
                              hipStream_t stream)
{
  (void)in_sizes; (void)n_in; (void)out_size; (void)ws_size;
  const int*   x     = (const int*)d_in[0];
  const float* embed = (const float*)d_in[1];
  const float* Wg    = (const float*)d_in[2];
  const float* bg    = (const float*)d_in[3];
  const float* W1    = (const float*)d_in[4];
  const float* b1    = (const float*)d_in[5];
  const float* W2    = (const float*)d_in[6];
  const float* b2    = (const float*)d_in[7];
  const float* gamma = (const float*)d_in[8];
  const float* beta  = (const float*)d_in[9];
  const float* Wh    = (const float*)d_in[10];
  const float* bh    = (const float*)d_in[11];
  float* out = (float*)d_out;

  char* ws = (char*)d_ws;
  size_t o = 0;
  int* ctl = (int*)(ws + o);        o += 1024;
  bf16* h_bf = (bf16*)(ws + o);     o += (size_t)TOKENS * DMODEL * 2;
  int* top2i = (int*)(ws + o);      o += (size_t)TOKENS * 2 * 4;
  float* top2w = (float*)(ws + o);  o += (size_t)TOKENS * 2 * 4;
  int* tok2row = (int*)(ws + o);    o += (size_t)TOKENS * 2 * 4;
  int* rowtok = (int*)(ws + o);     o += (size_t)ROWCAP * 4;
  o = (o + 255) & ~(size_t)255;
  bf16* a_act = (bf16*)(ws + o);    o += (size_t)ROWCAP * HID * 2;
  float* yrow = (float*)(ws + o);   o += (size_t)ROWCAP * DMODEL * 4;
  bf16* lnb = (bf16*)(ws + o);      o += (size_t)TOKENS * DMODEL * 2;
  bf16* W1t = (bf16*)(ws + o);      o += (size_t)NEXP * DMODEL * HID * 2;
  bf16* W2t = (bf16*)(ws + o);      o += (size_t)NEXP * DMODEL * HID * 2;
  bf16* Wht = (bf16*)(ws + o);      o += (size_t)DMODEL * VOCAB * 2;

  hipMemsetAsync(ctl, 0, CTL_INTS * sizeof(int), stream);
  embed_gate<<<TOKENS, 256, 0, stream>>>(x, embed, Wg, bg, h_bf, top2i, top2w, ctl);
  scatter_k<<<1, 256, 0, stream>>>(top2i, ctl, tok2row, rowtok);
  transpose_cvt<<<dim3(HID/32, DMODEL/32, NEXP), 256, 0, stream>>>(W1, W1t, DMODEL, HID);
  transpose_cvt<<<dim3(DMODEL/32, HID/32, NEXP), 256, 0, stream>>>(W2, W2t, HID, DMODEL);
  transpose_cvt<<<dim3(VOCAB/32, DMODEL/32, 1), 256, 0, stream>>>(Wh, Wht, DMODEL, VOCAB);
  gemm128<0><<<dim3(MAXTILES, HID/128), 256, 0, stream>>>(h_bf, W1t, b1, nullptr, a_act, ctl, rowtok);
  gemm128<1><<<dim3(MAXTILES, DMODEL/128), 256, 0, stream>>>(a_act, W2t, b2, yrow, nullptr, ctl, nullptr);
  combine_ln<<<TOKENS, 256, 0, stream>>>(yrow, tok2row, top2w, gamma, beta, lnb);

  // head GEMM: 256^2 8-phase pipeline, 128KB dynamic LDS (1 block/CU)
  hipFuncSetAttribute(reinterpret_cast<const void*>(gemm256),
                      hipFuncAttributeMaxDynamicSharedMemorySize, 131072);
  gemm256<<<dim3(8, VOCAB/256), 512, 131072, stream>>>(lnb, Wht, bh, out);
}

// Round 2
// 834.670 us; speedup vs baseline: 1.0384x; 1.0154x over previous
//
#include <hip/hip_runtime.h>
#include <hip/hip_bf16.h>
#include <stdint.h>

#define TOKENS 2048
#define DMODEL 1024
#define HID    2048
#define NEXP   8
#define VOCAB  32000
#define ROWCAP 5120      // 4096 rows + 8*127 pad, rounded to 40*128
#define MAXTILES 40
#define LN_EPS 1e-5f

typedef __hip_bfloat16 bf16;
typedef __bf16 v8bf __attribute__((ext_vector_type(8)));
typedef float  v4f  __attribute__((ext_vector_type(4)));

// control block (ints) at ws offset 0
#define CTL_COUNTS 0    // 8
#define CTL_CURSOR 8    // 8
#define CTL_PADOFF 16   // 9
#define CTL_TILE2E 32   // 40
#define CTL_NTILES 72
#define CTL_INTS   80

typedef __attribute__((address_space(3))) uint32_t lds_u32_t;
typedef __attribute__((address_space(1))) uint32_t glb_u32_t;

__device__ __forceinline__ void gl2lds16(const void* g, void* l) {
  // async global->LDS, 16B per lane; LDS dst is wave-uniform base + lane*16
  __builtin_amdgcn_global_load_lds((glb_u32_t*)(uintptr_t)g,
                                   (lds_u32_t*)(uintptr_t)l, 16, 0, 0);
}

// ---------------- embed gather + gate softmax + top2 ----------------
__global__ __launch_bounds__(256) void embed_gate(
    const int* __restrict__ x, const float* __restrict__ embed,
    const float* __restrict__ Wg, const float* __restrict__ bg,
    bf16* __restrict__ h_bf, int* __restrict__ top2i, float* __restrict__ top2w,
    int* __restrict__ ctl)
{
  const int t = blockIdx.x, tid = threadIdx.x;
  const int xid = x[t];
  const float4 hv = ((const float4*)(embed + (size_t)xid * DMODEL))[tid];

  union { ushort4 u; bf16 b[4]; } pk;
  pk.b[0] = __float2bfloat16(hv.x); pk.b[1] = __float2bfloat16(hv.y);
  pk.b[2] = __float2bfloat16(hv.z); pk.b[3] = __float2bfloat16(hv.w);
  ((ushort4*)(h_bf + (size_t)t * DMODEL))[tid] = pk.u;

  float acc[8] = {0,0,0,0,0,0,0,0};
  const float hk[4] = {hv.x, hv.y, hv.z, hv.w};
  #pragma unroll
  for (int u = 0; u < 4; ++u) {
    const float* wr = Wg + (size_t)(tid*4 + u) * NEXP;
    #pragma unroll
    for (int e = 0; e < 8; ++e) acc[e] += hk[u] * wr[e];
  }
  #pragma unroll
  for (int e = 0; e < 8; ++e)
    for (int off = 32; off >= 1; off >>= 1)
      acc[e] += __shfl_down(acc[e], off, 64);

  __shared__ float sred[4][8];
  const int lane = tid & 63, wave = tid >> 6;
  if (lane == 0) {
    #pragma unroll
    for (int e = 0; e < 8; ++e) sred[wave][e] = acc[e];
  }
  __syncthreads();
  if (tid == 0) {
    float lg[8];
    #pragma unroll
    for (int e = 0; e < 8; ++e)
      lg[e] = sred[0][e] + sred[1][e] + sred[2][e] + sred[3][e] + bg[e];
    float m = lg[0];
    #pragma unroll
    for (int e = 1; e < 8; ++e) m = fmaxf(m, lg[e]);
    float p[8], s = 0.f;
    #pragma unroll
    for (int e = 0; e < 8; ++e) { p[e] = expf(lg[e] - m); s += p[e]; }
    const float inv = 1.f / s;
    int i0 = 0;
    for (int e = 1; e < 8; ++e) if (p[e] > p[i0]) i0 = e;
    int i1 = -1;
    for (int e = 0; e < 8; ++e) { if (e == i0) continue; if (i1 < 0 || p[e] > p[i1]) i1 = e; }
    top2i[2*t] = i0; top2i[2*t+1] = i1;
    top2w[2*t] = p[i0]*inv; top2w[2*t+1] = p[i1]*inv;
    atomicAdd(&ctl[CTL_COUNTS + i0], 1);
    atomicAdd(&ctl[CTL_COUNTS + i1], 1);
  }
}

// ---------------- bucket tokens per expert (128-aligned segments) ----------------
__global__ __launch_bounds__(256) void scatter_k(
    const int* __restrict__ top2i, int* __restrict__ ctl,
    int* __restrict__ tok2row, int* __restrict__ rowtok)
{
  __shared__ int spad[8];
  const int tid = threadIdx.x;
  for (int r = tid; r < ROWCAP; r += 256) rowtok[r] = 0;   // pad rows -> token 0 (harmless)
  if (tid == 0) {
    int off = 0, gm = 0;
    for (int e = 0; e < 8; ++e) {
      spad[e] = off; ctl[CTL_PADOFF + e] = off;
      int nt = (ctl[CTL_COUNTS + e] + 127) >> 7;
      for (int i = 0; i < nt; ++i) ctl[CTL_TILE2E + gm++] = e;
      off += nt << 7;
    }
    ctl[CTL_PADOFF + 8] = off;
    ctl[CTL_NTILES] = gm;
  }
  __syncthreads();
  for (int idx = tid; idx < 2*TOKENS; idx += 256) {
    const int e = top2i[idx];
    const int pos = spad[e] + atomicAdd(&ctl[CTL_CURSOR + e], 1);
    tok2row[idx] = pos;
    rowtok[pos] = idx >> 1;
  }
}

// ---------------- fp32 [b][R][C] -> bf16 [b][C][R] (B^T layout for MFMA) ----------------
__global__ __launch_bounds__(256) void transpose_cvt(
    const float* __restrict__ in, bf16* __restrict__ out, int R, int C)
{
  __shared__ float tile[32][33];
  const int b = blockIdx.z;
  in  += (size_t)b * R * C;
  out += (size_t)b * R * C;
  const int ct = blockIdx.x * 32, rt = blockIdx.y * 32;
  const int lc = threadIdx.x & 31, lr = threadIdx.x >> 5;  // 0..31, 0..7
  #pragma unroll
  for (int i = 0; i < 4; ++i) {
    const int r = lr + i*8;
    tile[r][lc] = in[(size_t)(rt + r) * C + ct + lc];
  }
  __syncthreads();
  #pragma unroll
  for (int i = 0; i < 4; ++i) {
    const int r = lr + i*8;
    out[(size_t)(ct + r) * R + rt + lc] = __float2bfloat16(tile[lc][r]);
  }
}

// ---------------- 128x128x32 bf16 MFMA GEMM (m97 structure) ----------------
// MODE 0: a_act = relu(h[rowtok] @ W1t[e]^T + b1[e])  K=1024 N=2048, bf16 out
// MODE 1: y     =       a_act @ W2t[e]^T + b2[e]      K=2048 N=1024, f32 out
template<int MODE>
__global__ __launch_bounds__(256) void gemm128(
    const bf16* __restrict__ Abase, const bf16* __restrict__ Btbase,
    const float* __restrict__ bias, float* __restrict__ outF, bf16* __restrict__ outB,
    const int* __restrict__ ctl, const int* __restrict__ rowtok)
{
  constexpr int K = (MODE == 1) ? HID : DMODEL;
  constexpr int N = (MODE == 0) ? HID : DMODEL;
  const int gm = blockIdx.x, gn = blockIdx.y;

  int eid = 0;
  if (gm >= ctl[CTL_NTILES]) return;
  eid = ctl[CTL_TILE2E + gm];

  __shared__ bf16 As[128 * 32];
  __shared__ bf16 Bs[128 * 32];
  __shared__ int  rts[128];

  const int tid = threadIdx.x, lane = tid & 63, wave = tid >> 6;
  const bf16* Bt = Btbase + (size_t)eid * (size_t)N * K + (size_t)(gn * 128) * K;
  const float* bv = bias + (size_t)eid * N + gn * 128;

  if constexpr (MODE == 0) {
    if (tid < 128) rts[tid] = rowtok[gm * 128 + tid];
    __syncthreads();
  }

  // staging coords: chunk c = 16 rows; wave handles chunks {wave, wave+4}
  const int srow = lane >> 2;          // row within chunk
  const int scol = (lane & 3) * 8;     // bf16 col offset (16B granules)
  const int r0 = wave * 16 + srow, r1 = (wave + 4) * 16 + srow;
  size_t ga0, ga1;
  if constexpr (MODE == 0) { ga0 = (size_t)rts[r0]; ga1 = (size_t)rts[r1]; }
  else { ga0 = (size_t)(gm * 128 + r0); ga1 = (size_t)(gm * 128 + r1); }
  const bf16* aptr0 = Abase + ga0 * K + scol;
  const bf16* aptr1 = Abase + ga1 * K + scol;
  const bf16* bptr0 = Bt + (size_t)r0 * K + scol;
  const bf16* bptr1 = Bt + (size_t)r1 * K + scol;

  const int wm = (wave & 1) * 64, wn = (wave >> 1) * 64;
  const int lr = lane & 15, lq = lane >> 4;

  v4f acc[4][4] = {};

  for (int k0 = 0; k0 < K; k0 += 32) {
    gl2lds16(aptr0 + k0, &As[wave * 512]);
    gl2lds16(aptr1 + k0, &As[(wave + 4) * 512]);
    gl2lds16(bptr0 + k0, &Bs[wave * 512]);
    gl2lds16(bptr1 + k0, &Bs[(wave + 4) * 512]);
    __syncthreads();

    v8bf af[4], bfg[4];
    #pragma unroll
    for (int i = 0; i < 4; ++i) af[i]  = *(const v8bf*)&As[(wm + i*16 + lr) * 32 + lq * 8];
    #pragma unroll
    for (int j = 0; j < 4; ++j) bfg[j] = *(const v8bf*)&Bs[(wn + j*16 + lr) * 32 + lq * 8];
    #pragma unroll
    for (int i = 0; i < 4; ++i)
      #pragma unroll
      for (int j = 0; j < 4; ++j)
        acc[i][j] = __builtin_amdgcn_mfma_f32_16x16x32_bf16(af[i], bfg[j], acc[i][j], 0, 0, 0);
    __syncthreads();
  }

  float bb[4];
  #pragma unroll
  for (int j = 0; j < 4; ++j) bb[j] = bv[wn + j*16 + lr];

  #pragma unroll
  for (int i = 0; i < 4; ++i) {
    #pragma unroll
    for (int j = 0; j < 4; ++j) {
      #pragma unroll
      for (int r = 0; r < 4; ++r) {
        const int row = gm * 128 + wm + i*16 + lq*4 + r;
        const int col = gn * 128 + wn + j*16 + lr;
        float v = acc[i][j][r] + bb[j];
        if constexpr (MODE == 0) {
          v = v > 0.f ? v : 0.f;
          outB[(size_t)row * N + col] = __float2bfloat16(v);
        } else {
          outF[(size_t)row * (size_t)N + col] = v;
        }
      }
    }
  }
}

// ================= 256x256x64 8-phase head GEMM (T1+T2+T3+T4+T5) =================
// out[2048][32000] = lnb[2048][1024] @ Wht[32000][1024]^T + bh
// 8 waves (2M x 4N), per-wave 128x64 output. LDS 128KB: 2 dbuf x (A 32KB + B 32KB).
// LDS layout per matrix per buffer: [half h:2][kk:2][row:128][64B].
// Bank-conflict fix (round 2): granule-rotation swizzle within each 64B row.
//   physical slot of logical K-granule g in row r  =  g ^ ((r>>1)&3)
//   -> read bank-quad = (r*4 + slot)&7 covers all 8 quads over 8 consecutive rows
//      (2 lanes/quad per 16-lane group = free 2-way). Rule #21: LDS dest stays
//      LINEAR (global_load_lds), the global SOURCE granule is pre-swizzled, and
//      the ds_read offset applies the same XOR ((lr>>1)&3, lane-constant).
// Pipeline: per K-tile 4 phases; A(kt+1) halves staged at ph0/ph1, B(kt+2) halves
//   at ph2/ph3 into the just-freed B region. Single counted s_waitcnt vmcnt(4)
//   per K-tile -- never vmcnt(0) in steady state.

__device__ __forceinline__ void stageAB(const bf16* g, char* l) {
  gl2lds16(g,      l);          // kk=0 plane
  gl2lds16(g + 32, l + 8192);   // kk=1 plane
}

#define SBAR() do { __builtin_amdgcn_sched_barrier(0); \
                    __builtin_amdgcn_s_barrier();       \
                    __builtin_amdgcn_sched_barrier(0); } while (0)

__global__ __launch_bounds__(512, 2) void gemm256(
    const bf16* __restrict__ A, const bf16* __restrict__ Bt,
    const float* __restrict__ bias, float* __restrict__ out)
{
  extern __shared__ char smem[];
  constexpr int K = DMODEL;        // 1024
  constexpr int N = VOCAB;         // 32000
  constexpr int NK = K / 64;       // 16

  // XCD-chunked swizzle: 1000 wgs = 8 XCDs x 125; within a chunk m is fastest so
  // each XCD keeps the full 4MB A in its L2 and streams B panels once.
  const int orig = blockIdx.y * 8 + blockIdx.x;
  const int p = (orig & 7) * 125 + (orig >> 3);
  const int tm0 = (p & 7) * 256;
  const int tn0 = (p >> 3) * 256;

  const int tid = threadIdx.x;
  const int lane = tid & 63, wv = tid >> 6;
  const int lr = lane & 15, lq = lane >> 4;
  const int wr = wv >> 2, wc = wv & 3;

  // staging: thread t fills physical 16B granule t of each 8KB kk-plane.
  // physical (row, slot) = (t>>2, t&3) stores logical granule (t&3)^((t>>3)&3).
  const int r_s = tid >> 2;                                   // 0..127 row within half
  const int c_s = 8 * ((tid & 3) ^ ((tid >> 3) & 3));         // pre-swizzled source col
  const bf16* aG = A  + (size_t)(tm0 + r_s) * K + c_s;
  const bf16* bG = Bt + (size_t)(tn0 + r_s) * K + c_s;
  char* lW = smem + wv * 1024;              // wave-uniform 1KB window in each plane

  // fragment-read byte bases (add db*65536 + kk*8192 + frag*1024)
  const int slotSwz = (lq ^ ((lr >> 1) & 3)) * 16;            // swizzled read slot
  const int aOff = wr * 16384 + lr * 64 + slotSwz;
  const int bOff = 32768 + (wc >> 1) * 16384 + ((wc & 1) * 64 + lr) * 64 + slotSwz;

  v4f acc[8][4] = {};
  v8bf Af[4][2], Bf[4][2];

  // ---- prologue: stage tiles 0 (buf0) and 1 (buf1) = 16 loads/thread ----
  stageAB(aG,          lW);                       // A(0) h0
  stageAB(aG + 131072, lW + 16384);               // A(0) h1   (131072 = 128*K elems)
  stageAB(bG,          lW + 32768);               // B(0) h0
  stageAB(bG + 131072, lW + 32768 + 16384);       // B(0) h1
  stageAB(aG + 64,           lW + 65536);             // A(1) h0
  stageAB(aG + 131072 + 64,  lW + 65536 + 16384);     // A(1) h1
  stageAB(bG + 64,           lW + 65536 + 32768);     // B(1) h0
  stageAB(bG + 131072 + 64,  lW + 65536 + 32768 + 16384); // B(1) h1
  asm volatile("s_waitcnt vmcnt(8)" ::: "memory");  // tile 0 arrived; tile 1 in flight
  __builtin_amdgcn_s_barrier();
  __builtin_amdgcn_sched_barrier(0);

  for (int kt = 0; kt < NK; ++kt) {
    const int db = kt & 1;
    const char* sA = smem + db * 65536 + aOff;
    const char* sB = smem + db * 65536 + bOff;
    char* lwA = lW + (db ^ 1) * 65536;              // A(kt+1) -> other buffer
    char* lwB = lW + db * 65536 + 32768;            // B(kt+2) -> same-parity buffer
    const int kN1 = (kt + 1) * 64;
    const int kN2 = (kt + 2) * 64;
    const bool stA = (kt > 0) & (kt + 1 < NK);      // kt==0: A(1) staged in prologue
    const bool stB = (kt + 2 < NK);

    // ---- phase 0: read A m0-3 + B n0-1 (12 reads) | stage A(kt+1) h0 ----
    #pragma unroll
    for (int mi = 0; mi < 4; ++mi)
      #pragma unroll
      for (int kk = 0; kk < 2; ++kk)
        Af[mi][kk] = *(const v8bf*)(sA + kk * 8192 + mi * 1024);
    #pragma unroll
    for (int n = 0; n < 2; ++n)
      #pragma unroll
      for (int kk = 0; kk < 2; ++kk)
        Bf[n][kk] = *(const v8bf*)(sB + kk * 8192 + n * 1024);
    if (stA) stageAB(aG + kN1, lwA);
    SBAR();
    __builtin_amdgcn_s_setprio(1);
    #pragma unroll
    for (int mi = 0; mi < 4; ++mi)
      #pragma unroll
      for (int n = 0; n < 2; ++n) {
        acc[mi][n] = __builtin_amdgcn_mfma_f32_16x16x32_bf16(Af[mi][0], Bf[n][0], acc[mi][n], 0, 0, 0);
        acc[mi][n] = __builtin_amdgcn_mfma_f32_16x16x32_bf16(Af[mi][1], Bf[n][1], acc[mi][n], 0, 0, 0);
      }
    __builtin_amdgcn_s_setprio(0);
    SBAR();

    // ---- phase 1: read B n2-3 (4 reads) | stage A(kt+1) h1 ----
    #pragma unroll
    for (int n = 2; n < 4; ++n)
      #pragma unroll
      for (int kk = 0; kk < 2; ++kk)
        Bf[n][kk] = *(const v8bf*)(sB + kk * 8192 + n * 1024);
    if (stA) stageAB(aG + 131072 + kN1, lwA + 16384);
    SBAR();
    __builtin_amdgcn_s_setprio(1);
    #pragma unroll
    for (int mi = 0; mi < 4; ++mi)
      #pragma unroll
      for (int n = 2; n < 4; ++n) {
        acc[mi][n] = __builtin_amdgcn_mfma_f32_16x16x32_bf16(Af[mi][0], Bf[n][0], acc[mi][n], 0, 0, 0);
        acc[mi][n] = __builtin_amdgcn_mfma_f32_16x16x32_bf16(Af[mi][1], Bf[n][1], acc[mi][n], 0, 0, 0);
      }
    __builtin_amdgcn_s_setprio(0);
    SBAR();

    // ---- phase 2: read A m4-7 (8 reads) | stage B(kt+2) h0 (B region dead) ----
    #pragma unroll
    for (int mi = 0; mi < 4; ++mi)
      #pragma unroll
      for (int kk = 0; kk < 2; ++kk)
        Af[mi][kk] = *(const v8bf*)(sA + kk * 8192 + (4 + mi) * 1024);
    if (stB) stageAB(bG + kN2, lwB);
    SBAR();
    __builtin_amdgcn_s_setprio(1);
    #pragma unroll
    for (int mi = 0; mi < 4; ++mi)
      #pragma unroll
      for (int n = 2; n < 4; ++n) {
        acc[4 + mi][n] = __builtin_amdgcn_mfma_f32_16x16x32_bf16(Af[mi][0], Bf[n][0], acc[4 + mi][n], 0, 0, 0);
        acc[4 + mi][n] = __builtin_amdgcn_mfma_f32_16x16x32_bf16(Af[mi][1], Bf[n][1], acc[4 + mi][n], 0, 0, 0);
      }
    __builtin_amdgcn_s_setprio(0);
    SBAR();

    // ---- phase 3: stage B(kt+2) h1 | MFMA m4-7 x n0-1 | counted vmcnt boundary ----
    if (stB) stageAB(bG + 131072 + kN2, lwB + 16384);
    SBAR();
    __builtin_amdgcn_s_setprio(1);
    #pragma unroll
    for (int mi = 0; mi < 4; ++mi)
      #pragma unroll
      for (int n = 0; n < 2; ++n) {
        acc[4 + mi][n] = __builtin_amdgcn_mfma_f32_16x16x32_bf16(Af[mi][0], Bf[n][0], acc[4 + mi][n], 0, 0, 0);
        acc[4 + mi][n] = __builtin_amdgcn_mfma_f32_16x16x32_bf16(Af[mi][1], Bf[n][1], acc[4 + mi][n], 0, 0, 0);
      }
    __builtin_amdgcn_s_setprio(0);
    __builtin_amdgcn_sched_barrier(0);
    // boundary: A(kt+1)+B(kt+1) must have arrived; B(kt+2) (newest 4 loads) stays in flight
    if (stB) { asm volatile("s_waitcnt vmcnt(4)" ::: "memory"); }
    else     { asm volatile("s_waitcnt vmcnt(0)" ::: "memory"); }
    __builtin_amdgcn_s_barrier();
    __builtin_amdgcn_sched_barrier(0);
  }

  // ---- epilogue: bias + fp32 store ----
  const int col0 = tn0 + wc * 64 + lr;
  const size_t row0 = (size_t)(tm0 + wr * 128 + lq * 4);
  float bb[4];
  #pragma unroll
  for (int n = 0; n < 4; ++n) bb[n] = bias[col0 + n * 16];
  #pragma unroll
  for (int mi = 0; mi < 8; ++mi)
    #pragma unroll
    for (int n = 0; n < 4; ++n)
      #pragma unroll
      for (int rr = 0; rr < 4; ++rr)
        out[(row0 + mi * 16 + rr) * (size_t)N + col0 + n * 16] = acc[mi][n][rr] + bb[n];
}

// ---------------- combine top2 expert outputs + LayerNorm -> bf16 ----------------
__global__ __launch_bounds__(256) void combine_ln(
    const float* __restrict__ y, const int* __restrict__ tok2row,
    const float* __restrict__ top2w, const float* __restrict__ gamma,
    const float* __restrict__ beta, bf16* __restrict__ ln)
{
  const int t = blockIdx.x, tid = threadIdx.x;
  const int rr0 = tok2row[2*t], rr1 = tok2row[2*t+1];
  const float w0 = top2w[2*t], w1 = top2w[2*t+1];
  const float4 a = ((const float4*)(y + (size_t)rr0 * DMODEL))[tid];
  const float4 b = ((const float4*)(y + (size_t)rr1 * DMODEL))[tid];
  const float c0 = w0*a.x + w1*b.x, c1 = w0*a.y + w1*b.y;
  const float c2 = w0*a.z + w1*b.z, c3 = w0*a.w + w1*b.w;

  float s1 = c0 + c1 + c2 + c3;
  float s2 = c0*c0 + c1*c1 + c2*c2 + c3*c3;
  for (int off = 32; off >= 1; off >>= 1) {
    s1 += __shfl_down(s1, off, 64);
    s2 += __shfl_down(s2, off, 64);
  }
  __shared__ float rs1[4], rs2[4];
  __shared__ float smu, srs;
  const int lane = tid & 63, wave = tid >> 6;
  if (lane == 0) { rs1[wave] = s1; rs2[wave] = s2; }
  __syncthreads();
  if (tid == 0) {
    const float S1 = rs1[0] + rs1[1] + rs1[2] + rs1[3];
    const float S2 = rs2[0] + rs2[1] + rs2[2] + rs2[3];
    const float mu = S1 / DMODEL;
    const float var = S2 / DMODEL - mu * mu;
    smu = mu; srs = rsqrtf(var + LN_EPS);
  }
  __syncthreads();
  const float mu = smu, rstd = srs;
  const float4 g  = ((const float4*)gamma)[tid];
  const float4 be = ((const float4*)beta)[tid];
  union { ushort4 u; bf16 bb[4]; } pk;
  pk.bb[0] = __float2bfloat16((c0 - mu) * rstd * g.x + be.x);
  pk.bb[1] = __float2bfloat16((c1 - mu) * rstd * g.y + be.y);
  pk.bb[2] = __float2bfloat16((c2 - mu) * rstd * g.z + be.z);
  pk.bb[3] = __float2bfloat16((c3 - mu) * rstd * g.w + be.w);
  ((ushort4*)(ln + (size_t)t * DMODEL))[tid] = pk.u;
}

// ---------------- host ----------------
extern "C" void kernel_launch(void* const* d_in, const int* in_sizes, int n_in,
                              void* d_out, int out_size, void* d_ws, size_t ws_size,
                              hipStream_t stream)
{
  (void)in_sizes; (void)n_in; (void)out_size; (void)ws_size;
  const int*   x     = (const int*)d_in[0];
  const float* embed = (const float*)d_in[1];
  const float* Wg    = (const float*)d_in[2];
  const float* bg    = (const float*)d_in[3];
  const float* W1    = (const float*)d_in[4];
  const float* b1    = (const float*)d_in[5];
  const float* W2    = (const float*)d_in[6];
  const float* b2    = (const float*)d_in[7];
  const float* gamma = (const float*)d_in[8];
  const float* beta  = (const float*)d_in[9];
  const float* Wh    = (const float*)d_in[10];
  const float* bh    = (const float*)d_in[11];
  float* out = (float*)d_out;

  char* ws = (char*)d_ws;
  size_t o = 0;
  int* ctl = (int*)(ws + o);        o += 1024;
  bf16* h_bf = (bf16*)(ws + o);     o += (size_t)TOKENS * DMODEL * 2;
  int* top2i = (int*)(ws + o);      o += (size_t)TOKENS * 2 * 4;
  float* top2w = (float*)(ws + o);  o += (size_t)TOKENS * 2 * 4;
  int* tok2row = (int*)(ws + o);    o += (size_t)TOKENS * 2 * 4;
  int* rowtok = (int*)(ws + o);     o += (size_t)ROWCAP * 4;
  o = (o + 255) & ~(size_t)255;
  bf16* a_act = (bf16*)(ws + o);    o += (size_t)ROWCAP * HID * 2;
  float* yrow = (float*)(ws + o);   o += (size_t)ROWCAP * DMODEL * 4;
  bf16* lnb = (bf16*)(ws + o);      o += (size_t)TOKENS * DMODEL * 2;
  bf16* W1t = (bf16*)(ws + o);      o += (size_t)NEXP * DMODEL * HID * 2;
  bf16* W2t = (bf16*)(ws + o);      o += (size_t)NEXP * DMODEL * HID * 2;
  bf16* Wht = (bf16*)(ws + o);      o += (size_t)DMODEL * VOCAB * 2;

  hipMemsetAsync(ctl, 0, CTL_INTS * sizeof(int), stream);
  embed_gate<<<TOKENS, 256, 0, stream>>>(x, embed, Wg, bg, h_bf, top2i, top2w, ctl);
  scatter_k<<<1, 256, 0, stream>>>(top2i, ctl, tok2row, rowtok);
  transpose_cvt<<<dim3(HID/32, DMODEL/32, NEXP), 256, 0, stream>>>(W1, W1t, DMODEL, HID);
  transpose_cvt<<<dim3(DMODEL/32, HID/32, NEXP), 256, 0, stream>>>(W2, W2t, HID, DMODEL);
  transpose_cvt<<<dim3(VOCAB/32, DMODEL/32, 1), 256, 0, stream>>>(Wh, Wht, DMODEL, VOCAB);
  gemm128<0><<<dim3(MAXTILES, HID/128), 256, 0, stream>>>(h_bf, W1t, b1, nullptr, a_act, ctl, rowtok);
  gemm128<1><<<dim3(MAXTILES, DMODEL/128), 256, 0, stream>>>(a_act, W2t, b2, yrow, nullptr, ctl, nullptr);
  combine_ln<<<TOKENS, 256, 0, stream>>>(yrow, tok2row, top2w, gamma, beta, lnb);

  // head GEMM: 256^2 8-phase pipeline, 128KB dynamic LDS (1 block/CU)
  hipFuncSetAttribute(reinterpret_cast<const void*>(gemm256),
                      hipFuncAttributeMaxDynamicSharedMemorySize, 131072);
  gemm256<<<dim3(8, VOCAB/256), 512, 131072, stream>>>(lnb, Wht, bh, out);
}